// Round 1
// baseline (210.524 us; speedup 1.0000x reference)
//
#include <hip/hip_runtime.h>
#include <hip/hip_bf16.h>

// Flash-attention fwd: out = x + softmax(x @ y^T) @ y   (no scale, eval-mode dropout)
// B=8, Sx=Sy=2048, D=128, fp32 in/out, bf16 MFMA internally.

#define SX 2048
#define SY 2048
#define DD 128
#define QBLK 32          // Q rows per block (16 per wave)
#define KVBLK 64         // K/V rows per tile
#define NW 2             // waves per block
#define NTHREADS (NW * 64)
#define PLD 72           // P LDS row stride in bf16 elems (144 B, 16B-aligned, bank-spread)
#define LOG2E 1.4426950408889634f

typedef __attribute__((ext_vector_type(8))) __bf16 bf16x8;
typedef __attribute__((ext_vector_type(4))) float f32x4;

__global__ __launch_bounds__(NTHREADS) void attn_fwd(
    const float* __restrict__ xg, const float* __restrict__ yg,
    float* __restrict__ og)
{
    const int tid  = (int)threadIdx.x;
    const int lane = tid & 63;
    const int wv   = tid >> 6;
    const int l15  = lane & 15;
    const int l4   = lane >> 4;      // 0..3
    const int batch = blockIdx.y;
    const int qbase = blockIdx.x * QBLK;

    const float* xb = xg + (size_t)batch * SX * DD;
    const float* yb = yg + (size_t)batch * SY * DD;
    float*       ob = og + (size_t)batch * SX * DD;

    // K row-major [KVBLK][128] bf16, XOR-swizzled; V transposed [128][KVBLK], XOR-swizzled.
    __shared__ __align__(16) __bf16 Kl[KVBLK * DD];
    __shared__ __align__(16) __bf16 Vt[DD * KVBLK];
    __shared__ __align__(16) __bf16 Pl[NW][16 * PLD];

    char* Kb = (char*)Kl;
    char* Vb = (char*)Vt;
    __bf16* Pw = &Pl[wv][0];

    // ---- Q fragments in registers: A-layout row = l15, k = k0*32 + l4*8 + j ----
    const int qrow = qbase + wv * 16 + l15;
    bf16x8 aq[4];
#pragma unroll
    for (int k0 = 0; k0 < 4; ++k0) {
        const float* qp = xb + (size_t)qrow * DD + k0 * 32 + l4 * 8;
        f32x4 q0 = *(const f32x4*)qp;
        f32x4 q1 = *(const f32x4*)(qp + 4);
        bf16x8 v;
#pragma unroll
        for (int j = 0; j < 4; ++j) { v[j] = (__bf16)q0[j]; v[4 + j] = (__bf16)q1[j]; }
        aq[k0] = v;
    }

    f32x4 o[8];
#pragma unroll
    for (int i = 0; i < 8; ++i) o[i] = f32x4{0.f, 0.f, 0.f, 0.f};
    float m[4], ls[4];
#pragma unroll
    for (int r = 0; r < 4; ++r) { m[r] = -3.0e38f; ls[r] = 0.f; }

    for (int kv0 = 0; kv0 < SY; kv0 += KVBLK) {
        __syncthreads();
        // ---- stage y tile: fp32 -> bf16, K row-major + V transposed, both swizzled ----
#pragma unroll
        for (int t = 0; t < (KVBLK * DD / 8) / NTHREADS; ++t) {
            int cid = t * NTHREADS + tid;
            int row = cid >> 4;       // 0..63
            int c8  = cid & 15;       // 8-col chunk
            const float* gp = yb + (size_t)(kv0 + row) * DD + c8 * 8;
            f32x4 u0 = *(const f32x4*)gp;
            f32x4 u1 = *(const f32x4*)(gp + 4);
            bf16x8 kv;
#pragma unroll
            for (int j = 0; j < 4; ++j) { kv[j] = (__bf16)u0[j]; kv[4 + j] = (__bf16)u1[j]; }
            int ka = (row * 256 + c8 * 16) ^ ((row & 7) << 4);
            *(bf16x8*)(Kb + ka) = kv;
#pragma unroll
            for (int j = 0; j < 8; ++j) {
                int d = c8 * 8 + j;                       // d & 7 == j
                int va = (d * 128 + row * 2) ^ ((j & 7) << 4);
                *(__bf16*)(Vb + va) = kv[j];
            }
        }
        __syncthreads();

        // ---- S = Q K^T : 16x64 per wave ----
        f32x4 sc[4];
#pragma unroll
        for (int ct = 0; ct < 4; ++ct) {
            sc[ct] = f32x4{0.f, 0.f, 0.f, 0.f};
            int krow = ct * 16 + l15;
            int swz = (krow & 7) << 4;
#pragma unroll
            for (int k0 = 0; k0 < 4; ++k0) {
                bf16x8 kb = *(const bf16x8*)(Kb + ((krow * 256 + k0 * 64 + l4 * 16) ^ swz));
                sc[ct] = __builtin_amdgcn_mfma_f32_16x16x32_bf16(aq[k0], kb, sc[ct], 0, 0, 0);
            }
        }

        // ---- online softmax (rows r live in 16-lane column groups; reduce via shfl_xor) ----
        float al[4];
#pragma unroll
        for (int r = 0; r < 4; ++r) {
            float v = fmaxf(fmaxf(sc[0][r], sc[1][r]), fmaxf(sc[2][r], sc[3][r]));
#pragma unroll
            for (int off = 1; off < 16; off <<= 1)
                v = fmaxf(v, __shfl_xor(v, off, 64));
            float mn = fmaxf(m[r], v);
            al[r] = __builtin_exp2f((m[r] - mn) * LOG2E);
            m[r] = mn;
            int prow = 4 * l4 + r;
            float ps = 0.f;
#pragma unroll
            for (int ct = 0; ct < 4; ++ct) {
                float p = __builtin_exp2f((sc[ct][r] - mn) * LOG2E);
                ps += p;
                Pw[prow * PLD + ct * 16 + l15] = (__bf16)p;
            }
#pragma unroll
            for (int off = 1; off < 16; off <<= 1)
                ps += __shfl_xor(ps, off, 64);
            ls[r] = ls[r] * al[r] + ps;
        }
#pragma unroll
        for (int dt = 0; dt < 8; ++dt)
#pragma unroll
            for (int r = 0; r < 4; ++r)
                o[dt][r] *= al[r];

        // P_lds writes -> reads are same-wave; make the wait explicit.
        asm volatile("s_waitcnt lgkmcnt(0)" ::: "memory");

        // ---- O += P V ----
#pragma unroll
        for (int j0 = 0; j0 < 2; ++j0) {
            bf16x8 pa = *(const bf16x8*)((char*)Pw + l15 * (PLD * 2) + j0 * 64 + l4 * 16);
#pragma unroll
            for (int dt = 0; dt < 8; ++dt) {
                int d = dt * 16 + l15;
                bf16x8 vb = *(const bf16x8*)(Vb + ((d * 128 + j0 * 64 + l4 * 16) ^ ((d & 7) << 4)));
                o[dt] = __builtin_amdgcn_mfma_f32_16x16x32_bf16(pa, vb, o[dt], 0, 0, 0);
            }
        }
    }

    // ---- epilogue: out = x + O / l ----
#pragma unroll
    for (int dt = 0; dt < 8; ++dt) {
#pragma unroll
        for (int r = 0; r < 4; ++r) {
            int row = qbase + wv * 16 + 4 * l4 + r;
            int col = dt * 16 + l15;
            size_t idx = (size_t)row * DD + col;
            ob[idx] = xb[idx] + o[dt][r] / ls[r];
        }
    }
}

extern "C" void kernel_launch(void* const* d_in, const int* in_sizes, int n_in,
                              void* d_out, int out_size, void* d_ws, size_t ws_size,
                              hipStream_t stream) {
    const float* x = (const float*)d_in[0];
    const float* y = (const float*)d_in[1];
    float* out = (float*)d_out;
    int nb = in_sizes[0] / (SX * DD);   // 8
    dim3 grid(SX / QBLK, nb);
    attn_fwd<<<grid, NTHREADS, 0, stream>>>(x, y, out);
}

// Round 2
// 135.037 us; speedup vs baseline: 1.5590x; 1.5590x over previous
//
#include <hip/hip_runtime.h>
#include <hip/hip_fp16.h>

// out = x + softmax(x @ y^T) @ y ; B=8, S=2048, D=128, fp32 in/out, f16 MFMA inside.
// Structure: prepass (y -> f16 yB row-major + yT transposed) ;
//            attn_fwd with KV-split=2 (partials to ws) ; combine (+residual).

#define SX 2048
#define SY 2048
#define DD 128
#define QBLK 32
#define KVBLK 64
#define NW 2
#define NTHREADS (NW * 64)
#define LOG2E 1.4426950408889634f

typedef __attribute__((ext_vector_type(8))) _Float16 f16x8;
typedef __attribute__((ext_vector_type(4))) float f32x4;

// ---------------- prepass: y fp32 [B][SY][DD] -> yB f16 [B][SY][DD], yT f16 [B][DD][SY]
__global__ __launch_bounds__(256) void prepass(const float* __restrict__ y,
                                               _Float16* __restrict__ yB,
                                               _Float16* __restrict__ yT)
{
    __shared__ _Float16 T[64 * 64];   // [k][d] tile, swizzled
    char* Tb = (char*)T;
    const int tid = (int)threadIdx.x;
    const int b = blockIdx.y;
    const int k0 = (blockIdx.x >> 1) * 64;
    const int d0 = (blockIdx.x & 1) * 64;
    const float* yb = y + (size_t)b * SY * DD;
#pragma unroll
    for (int t = 0; t < 2; ++t) {
        int cid = t * 256 + tid;
        int row = cid >> 3, c = cid & 7;
        const float* gp = yb + (size_t)(k0 + row) * DD + d0 + c * 8;
        f32x4 a0 = *(const f32x4*)gp;
        f32x4 a1 = *(const f32x4*)(gp + 4);
        f16x8 v;
#pragma unroll
        for (int j = 0; j < 4; ++j) { v[j] = (_Float16)a0[j]; v[4 + j] = (_Float16)a1[j]; }
        *(f16x8*)(yB + ((size_t)b * SY + k0 + row) * DD + d0 + c * 8) = v;
        *(f16x8*)(Tb + ((row * 128 + c * 16) ^ ((row & 7) << 4))) = v;
    }
    __syncthreads();
#pragma unroll
    for (int t = 0; t < 2; ++t) {
        int cid = t * 256 + tid;
        int drow = cid >> 3, ck = cid & 7;
        f16x8 v;
#pragma unroll
        for (int j = 0; j < 8; ++j)
            v[j] = *(const _Float16*)(Tb + ((((ck * 8 + j) * 128) + drow * 2) ^ (j << 4)));
        *(f16x8*)(yT + ((size_t)b * DD + d0 + drow) * SY + k0 + ck * 8) = v;
    }
}

// ---------------- attention ----------------
template<bool PRE, bool SPLITOUT>
__global__ __launch_bounds__(NTHREADS) void attn_fwd(
    const float* __restrict__ xg, const float* __restrict__ yg,
    const _Float16* __restrict__ yB, const _Float16* __restrict__ yT,
    float* __restrict__ og, float* __restrict__ Opart,
    float* __restrict__ mpart, float* __restrict__ lpart,
    int kv_len, int nb)
{
    const int tid = (int)threadIdx.x;
    const int lane = tid & 63;
    const int wv = tid >> 6;
    const int l15 = lane & 15;
    const int l4 = lane >> 4;
    const int b = blockIdx.y;
    const int qbase = blockIdx.x * QBLK;
    const int sp = blockIdx.z;
    const int kv_begin = sp * kv_len;

    const float* xb = xg + (size_t)b * SX * DD;

    __shared__ _Float16 Kl[KVBLK * DD];      // [k][d] swizzled (16 KB)
    __shared__ _Float16 Vt[DD * KVBLK];      // [d][k] swizzled (16 KB)
    __shared__ _Float16 Pl[NW][16 * DD];     // per-wave [row][k] swizzled (8 KB)
    char* Kb = (char*)Kl;
    char* Vb = (char*)Vt;
    char* Pw = (char*)&Pl[wv][0];

    // Q fragments: A-layout row=l15, k = k0i*32 + l4*8 + j
    const int qrow = qbase + wv * 16 + l15;
    f16x8 aq[4];
#pragma unroll
    for (int k0i = 0; k0i < 4; ++k0i) {
        const float* qp = xb + (size_t)qrow * DD + k0i * 32 + l4 * 8;
        f32x4 q0 = *(const f32x4*)qp;
        f32x4 q1 = *(const f32x4*)(qp + 4);
        f16x8 v;
#pragma unroll
        for (int j = 0; j < 4; ++j) { v[j] = (_Float16)q0[j]; v[4 + j] = (_Float16)q1[j]; }
        aq[k0i] = v;
    }

    f32x4 o[8];
#pragma unroll
    for (int i = 0; i < 8; ++i) o[i] = f32x4{0.f, 0.f, 0.f, 0.f};
    float m[4], ls[4];
#pragma unroll
    for (int r = 0; r < 4; ++r) { m[r] = -3.0e38f; ls[r] = 0.f; }

    for (int kv0 = kv_begin; kv0 < kv_begin + kv_len; kv0 += KVBLK) {
        __syncthreads();
        if constexpr (PRE) {
            const _Float16* ySrc = yB + ((size_t)b * SY + kv0) * DD;
            const _Float16* yTs = yT + (size_t)b * DD * SY + kv0;
#pragma unroll
            for (int t = 0; t < 8; ++t) {
                int cid = t * NTHREADS + tid;
                int row = cid >> 4, c8 = cid & 15;
                f16x8 kvv = *(const f16x8*)(ySrc + (size_t)row * DD + c8 * 8);
                *(f16x8*)(Kb + ((row * 256 + c8 * 16) ^ ((row & 7) << 4))) = kvv;
            }
#pragma unroll
            for (int t = 0; t < 8; ++t) {
                int cid = t * NTHREADS + tid;
                int d = cid >> 3, kc = cid & 7;
                f16x8 vv = *(const f16x8*)(yTs + (size_t)d * SY + kc * 8);
                *(f16x8*)(Vb + ((d * 128 + kc * 16) ^ ((d & 7) << 4))) = vv;
            }
        } else {
            const float* yb = yg + (size_t)b * SY * DD;
#pragma unroll
            for (int t = 0; t < 8; ++t) {
                int cid = t * NTHREADS + tid;
                int row = cid >> 4, c8 = cid & 15;
                const float* gp = yb + (size_t)(kv0 + row) * DD + c8 * 8;
                f32x4 u0 = *(const f32x4*)gp;
                f32x4 u1 = *(const f32x4*)(gp + 4);
                f16x8 kvv;
#pragma unroll
                for (int j = 0; j < 4; ++j) { kvv[j] = (_Float16)u0[j]; kvv[4 + j] = (_Float16)u1[j]; }
                *(f16x8*)(Kb + ((row * 256 + c8 * 16) ^ ((row & 7) << 4))) = kvv;
#pragma unroll
                for (int j = 0; j < 8; ++j) {
                    int d = c8 * 8 + j;
                    *(_Float16*)(Vb + ((d * 128 + row * 2) ^ ((j & 7) << 4))) = kvv[j];
                }
            }
        }
        __syncthreads();

        // ---- S = Q K^T : 16x64 per wave ----
        f32x4 sc[4];
#pragma unroll
        for (int ct = 0; ct < 4; ++ct) {
            sc[ct] = f32x4{0.f, 0.f, 0.f, 0.f};
            int krow = ct * 16 + l15;
            int swz = (l15 & 7) << 4;
#pragma unroll
            for (int k0i = 0; k0i < 4; ++k0i) {
                f16x8 kb = *(const f16x8*)(Kb + ((krow * 256 + k0i * 64 + l4 * 16) ^ swz));
                sc[ct] = __builtin_amdgcn_mfma_f32_16x16x32_f16(aq[k0i], kb, sc[ct], 0, 0, 0);
            }
        }

        // ---- online softmax ----
        float al[4];
#pragma unroll
        for (int r = 0; r < 4; ++r) {
            float v = fmaxf(fmaxf(sc[0][r], sc[1][r]), fmaxf(sc[2][r], sc[3][r]));
#pragma unroll
            for (int off = 1; off < 16; off <<= 1)
                v = fmaxf(v, __shfl_xor(v, off, 64));
            float mn = fmaxf(m[r], v);
            al[r] = __builtin_exp2f((m[r] - mn) * LOG2E);
            m[r] = mn;
            int prow = 4 * l4 + r;
            int pswz = (prow & 7) << 4;
            float ps = 0.f;
#pragma unroll
            for (int ct = 0; ct < 4; ++ct) {
                float p = __builtin_exp2f((sc[ct][r] - mn) * LOG2E);
                ps += p;
                *(_Float16*)(Pw + ((prow * 256 + (ct * 16 + l15) * 2) ^ pswz)) = (_Float16)p;
            }
#pragma unroll
            for (int off = 1; off < 16; off <<= 1)
                ps += __shfl_xor(ps, off, 64);
            ls[r] = ls[r] * al[r] + ps;
        }
#pragma unroll
        for (int dt = 0; dt < 8; ++dt)
#pragma unroll
            for (int r = 0; r < 4; ++r)
                o[dt][r] *= al[r];

        asm volatile("s_waitcnt lgkmcnt(0)" ::: "memory");

        // ---- O += P V ----
#pragma unroll
        for (int j0 = 0; j0 < 2; ++j0) {
            f16x8 pa = *(const f16x8*)(Pw + ((l15 * 256 + j0 * 64 + l4 * 16) ^ ((l15 & 7) << 4)));
#pragma unroll
            for (int dt = 0; dt < 8; ++dt) {
                int d = dt * 16 + l15;
                f16x8 vb = *(const f16x8*)(Vb + ((d * 128 + j0 * 64 + l4 * 16) ^ ((d & 7) << 4)));
                o[dt] = __builtin_amdgcn_mfma_f32_16x16x32_f16(pa, vb, o[dt], 0, 0, 0);
            }
        }
    }

    // ---- epilogue ----
    if constexpr (SPLITOUT) {
        float* Ob = Opart + ((size_t)sp * nb + b) * SX * DD;
#pragma unroll
        for (int dt = 0; dt < 8; ++dt)
#pragma unroll
            for (int r = 0; r < 4; ++r) {
                int row = qbase + wv * 16 + 4 * l4 + r;
                Ob[(size_t)row * DD + dt * 16 + l15] = o[dt][r];
            }
        if (l15 == 0) {
#pragma unroll
            for (int r = 0; r < 4; ++r) {
                int row = qbase + wv * 16 + 4 * l4 + r;
                mpart[((size_t)sp * nb + b) * SX + row] = m[r];
                lpart[((size_t)sp * nb + b) * SX + row] = ls[r];
            }
        }
    } else {
        float* ob = og + (size_t)b * SX * DD;
#pragma unroll
        for (int dt = 0; dt < 8; ++dt)
#pragma unroll
            for (int r = 0; r < 4; ++r) {
                int row = qbase + wv * 16 + 4 * l4 + r;
                int col = dt * 16 + l15;
                size_t idx = (size_t)row * DD + col;
                ob[idx] = xb[idx] + o[dt][r] / ls[r];
            }
    }
}

// ---------------- combine 2 splits + residual ----------------
__global__ __launch_bounds__(256) void combine(const float* __restrict__ x,
    const float* __restrict__ Opart, const float* __restrict__ mpart,
    const float* __restrict__ lpart, float* __restrict__ out, int nb)
{
    int tid = (int)threadIdx.x;
    int gr = blockIdx.x * 8 + (tid >> 5);        // global row in [0, nb*SX)
    int c4 = tid & 31;
    size_t nrows = (size_t)nb * SX;
    float m0 = mpart[gr], m1 = mpart[nrows + gr];
    float l0 = lpart[gr], l1 = lpart[nrows + gr];
    float M = fmaxf(m0, m1);
    float w0 = __builtin_exp2f((m0 - M) * LOG2E);
    float w1 = __builtin_exp2f((m1 - M) * LOG2E);
    float inv = 1.f / (l0 * w0 + l1 * w1);
    size_t off = (size_t)gr * DD + c4 * 4;
    f32x4 o0 = *(const f32x4*)(Opart + off);
    f32x4 o1 = *(const f32x4*)(Opart + nrows * DD + off);
    f32x4 xv = *(const f32x4*)(x + off);
    f32x4 rs;
#pragma unroll
    for (int j = 0; j < 4; ++j) rs[j] = xv[j] + (o0[j] * w0 + o1[j] * w1) * inv;
    *(f32x4*)(out + off) = rs;
}

extern "C" void kernel_launch(void* const* d_in, const int* in_sizes, int n_in,
                              void* d_out, int out_size, void* d_ws, size_t ws_size,
                              hipStream_t stream) {
    const float* x = (const float*)d_in[0];
    const float* y = (const float*)d_in[1];
    float* out = (float*)d_out;
    int nb = in_sizes[0] / (SX * DD);

    size_t yBsz = (size_t)nb * SY * DD * sizeof(_Float16);
    size_t yTsz = yBsz;
    size_t Osz = 2 * (size_t)nb * SX * DD * sizeof(float);
    size_t mlsz = 2 * (size_t)nb * SX * sizeof(float);
    char* w = (char*)d_ws;
    _Float16* yB = (_Float16*)w;
    _Float16* yT = (_Float16*)(w + yBsz);
    float* Op = (float*)(w + yBsz + yTsz);
    float* mp = (float*)(w + yBsz + yTsz + Osz);
    float* lp = (float*)(w + yBsz + yTsz + Osz + mlsz);
    size_t need_split = yBsz + yTsz + Osz + 2 * mlsz;
    size_t need_pre = yBsz + yTsz;

    if (ws_size >= need_split) {
        prepass<<<dim3((SY / 64) * (DD / 64), nb), 256, 0, stream>>>(y, yB, yT);
        attn_fwd<true, true><<<dim3(SX / QBLK, nb, 2), NTHREADS, 0, stream>>>(
            x, y, yB, yT, out, Op, mp, lp, SY / 2, nb);
        combine<<<dim3(nb * SX / 8), 256, 0, stream>>>(x, Op, mp, lp, out, nb);
    } else if (ws_size >= need_pre) {
        prepass<<<dim3((SY / 64) * (DD / 64), nb), 256, 0, stream>>>(y, yB, yT);
        attn_fwd<true, false><<<dim3(SX / QBLK, nb, 1), NTHREADS, 0, stream>>>(
            x, y, yB, yT, out, nullptr, nullptr, nullptr, SY, nb);
    } else {
        attn_fwd<false, false><<<dim3(SX / QBLK, nb, 1), NTHREADS, 0, stream>>>(
            x, y, nullptr, nullptr, out, nullptr, nullptr, nullptr, SY, nb);
    }
}

// Round 3
// 51.373 us; speedup vs baseline: 4.0979x; 2.6285x over previous
//
#include <hip/hip_runtime.h>
#include <hip/hip_fp16.h>

// out = x + softmax(x @ y^T) @ y ; B=8, S=2048, D=128, fp32 I/O, f16 MFMA (32x32x16).
// Structure: prepass (y -> yT f16 [B][D][SY]) ; attn 8-wave swapped-QK^T, KV-split=4 ;
//            combine (LSE merge + residual).

#define SX 2048
#define SY 2048
#define DD 128
#define KVBLK 64
#define NWAVE 8
#define QBLK (NWAVE * 32)     // 256 q rows per block
#define NTHREADS (NWAVE * 64) // 512
#define L2E 1.4426950408889634f

typedef __attribute__((ext_vector_type(8))) _Float16 f16x8;
typedef __attribute__((ext_vector_type(4))) _Float16 f16x4;
typedef __attribute__((ext_vector_type(4))) float f32x4;
typedef __attribute__((ext_vector_type(16))) float f32x16;
typedef __attribute__((ext_vector_type(4))) unsigned int u32x4;

// ---------------- prepass: y fp32 [B][SY][D] -> yT f16 [B][D][SY] ----------------
__global__ __launch_bounds__(256) void prepass(const float* __restrict__ y,
                                               _Float16* __restrict__ yT)
{
    __shared__ _Float16 T[64 * 64];
    char* Tb = (char*)T;
    const int tid = (int)threadIdx.x;
    const int b = blockIdx.y;
    const int k0 = (blockIdx.x >> 1) * 64;
    const int d0 = (blockIdx.x & 1) * 64;
    const float* yb = y + (size_t)b * SY * DD;
#pragma unroll
    for (int t = 0; t < 2; ++t) {
        int cid = t * 256 + tid;
        int row = cid >> 3, c = cid & 7;
        const float* gp = yb + (size_t)(k0 + row) * DD + d0 + c * 8;
        f32x4 a0 = *(const f32x4*)gp;
        f32x4 a1 = *(const f32x4*)(gp + 4);
        f16x8 v;
#pragma unroll
        for (int j = 0; j < 4; ++j) { v[j] = (_Float16)a0[j]; v[4 + j] = (_Float16)a1[j]; }
        *(f16x8*)(Tb + ((row * 128 + c * 16) ^ ((row & 7) << 4))) = v;
    }
    __syncthreads();
#pragma unroll
    for (int t = 0; t < 2; ++t) {
        int cid = t * 256 + tid;
        int drow = cid >> 3, ck = cid & 7;
        f16x8 v;
#pragma unroll
        for (int j = 0; j < 8; ++j)
            v[j] = *(const _Float16*)(Tb + ((((ck * 8 + j) * 128) + drow * 2) ^ (j << 4)));
        *(f16x8*)(yT + ((size_t)b * DD + d0 + drow) * SY + k0 + ck * 8) = v;
    }
}

// ---------------- attention: 8 waves, 32x32x16 swapped QK^T ----------------
template<bool SPLITOUT, bool USEYT>
__global__ __launch_bounds__(NTHREADS) void attn_fwd(
    const float* __restrict__ xg, const float* __restrict__ yg,
    const _Float16* __restrict__ yT,
    float* __restrict__ og, _Float16* __restrict__ Opart,
    float* __restrict__ mpart, float* __restrict__ lpart,
    int kv_len, int nb)
{
    __shared__ __align__(16) unsigned char smem[32768];
    char* Kb = (char*)smem;             // K tile [64][128] f16 swizzled (16KB)
    char* Vb = (char*)smem + 16384;     // V^T tile [128][64] f16 swizzled (16KB)

    const int tid = (int)threadIdx.x;
    const int lane = tid & 63;
    const int wv = tid >> 6;
    const int l31 = lane & 31;
    const int hi = lane >> 5;
    const int swz = (l31 & 7) << 4;
    const int b = blockIdx.y;
    const int qbase = blockIdx.x * QBLK;
    const int sp = blockIdx.z;
    const int kv_begin = sp * kv_len;
    const int ntiles = kv_len / KVBLK;

    const float* xb = xg + (size_t)b * SX * DD;
    const float* yb = yg + (size_t)b * SY * DD;

    // ---- Q fragments (B-operand): qreg[kst][j] = Q[qrow][kst*16 + hi*8 + j] ----
    const int qrow = qbase + wv * 32 + l31;
    f16x8 qreg[8];
#pragma unroll
    for (int kst = 0; kst < 8; ++kst) {
        const float* qp = xb + (size_t)qrow * DD + kst * 16 + hi * 8;
        f32x4 q0 = *(const f32x4*)qp;
        f32x4 q1 = *(const f32x4*)(qp + 4);
        f16x8 v;
#pragma unroll
        for (int j = 0; j < 4; ++j) { v[j] = (_Float16)q0[j]; v[4 + j] = (_Float16)q1[j]; }
        qreg[kst] = v;
    }

    // staged regs for next tile (T14 async-STAGE)
    f32x4 ks[4];   // K: 2 chunks x 8 f32
    f16x8 vs[2];   // V: 2 chunks (USEYT)

    auto LOADT = [&](int kv0) {
#pragma unroll
        for (int c = 0; c < 2; ++c) {
            int cid = c * NTHREADS + tid;
            int krow = cid >> 4, kc8 = cid & 15;
            const float* gp = yb + (size_t)(kv0 + krow) * DD + kc8 * 8;
            ks[c * 2]     = *(const f32x4*)gp;
            ks[c * 2 + 1] = *(const f32x4*)(gp + 4);
        }
        if constexpr (USEYT) {
#pragma unroll
            for (int c = 0; c < 2; ++c) {
                int cid = c * NTHREADS + tid;
                int d = cid >> 3, kc = cid & 7;
                vs[c] = *(const f16x8*)(yT + ((size_t)b * DD + d) * SY + kv0 + kc * 8);
            }
        }
    };
    auto STORET = [&]() {
#pragma unroll
        for (int c = 0; c < 2; ++c) {
            int cid = c * NTHREADS + tid;
            int krow = cid >> 4, kc8 = cid & 15;
            f16x8 kv;
#pragma unroll
            for (int j = 0; j < 4; ++j) { kv[j] = (_Float16)ks[c * 2][j]; kv[4 + j] = (_Float16)ks[c * 2 + 1][j]; }
            *(f16x8*)(Kb + ((krow * 256 + kc8 * 16) ^ ((krow & 7) << 4))) = kv;
            if constexpr (!USEYT) {
#pragma unroll
                for (int j = 0; j < 8; ++j) {
                    int d = kc8 * 8 + j;
                    *(_Float16*)(Vb + ((d * 128 + krow * 2) ^ ((d & 7) << 4))) = kv[j];
                }
            }
        }
        if constexpr (USEYT) {
#pragma unroll
            for (int c = 0; c < 2; ++c) {
                int cid = c * NTHREADS + tid;
                int d = cid >> 3, kc = cid & 7;
                *(f16x8*)(Vb + ((d * 128 + kc * 16) ^ ((d & 7) << 4))) = vs[c];
            }
        }
    };

    f32x16 o[4];
#pragma unroll
    for (int dt = 0; dt < 4; ++dt) o[dt] = f32x16{};
    float m = -3.0e38f, ls = 0.f;

    LOADT(kv_begin);
    for (int t = 0; t < ntiles; ++t) {
        __syncthreads();                 // all waves done reading previous tile
        STORET();
        if (t + 1 < ntiles) LOADT(kv_begin + (t + 1) * KVBLK);   // issue early (T14)
        __syncthreads();                 // tile ready

        // ---- S^T = K Q^T : two 32x32 subtiles, 8 k-steps of 16 ----
        f32x16 sc[2];
        __builtin_amdgcn_s_setprio(1);
#pragma unroll
        for (int s = 0; s < 2; ++s) {
            f32x16 acc = f32x16{};
#pragma unroll
            for (int kst = 0; kst < 8; ++kst) {
                f16x8 kf = *(const f16x8*)(Kb + (((32 * s + l31) * 256 + kst * 32 + hi * 16) ^ swz));
                acc = __builtin_amdgcn_mfma_f32_32x32x16_f16(kf, qreg[kst], acc, 0, 0, 0);
            }
            sc[s] = acc;
        }
        __builtin_amdgcn_s_setprio(0);

        // ---- online softmax, fully in-register (lane owns one q row) ----
        float tv[16];
#pragma unroll
        for (int r = 0; r < 16; ++r) tv[r] = fmaxf(sc[0][r], sc[1][r]);
#pragma unroll
        for (int st = 8; st >= 1; st >>= 1)
#pragma unroll
            for (int i = 0; i < 8; ++i)
                if (i < st) tv[i] = fmaxf(tv[i], tv[i + st]);
        float tm = tv[0];
        tm = fmaxf(tm, __shfl_xor(tm, 32, 64));
        float mn = fmaxf(m, tm);
        float al = __builtin_exp2f((m - mn) * L2E);
        float mnl = mn * L2E;
        m = mn;
        float sv[16];
#pragma unroll
        for (int r = 0; r < 16; ++r) {
            float p0 = __builtin_exp2f(__builtin_fmaf(sc[0][r], L2E, -mnl));
            float p1 = __builtin_exp2f(__builtin_fmaf(sc[1][r], L2E, -mnl));
            sc[0][r] = p0; sc[1][r] = p1;
            sv[r] = p0 + p1;
        }
#pragma unroll
        for (int st = 8; st >= 1; st >>= 1)
#pragma unroll
            for (int i = 0; i < 8; ++i)
                if (i < st) sv[i] += sv[i + st];
        float ps = sv[0];
        ps += __shfl_xor(ps, 32, 64);
        ls = ls * al + ps;
#pragma unroll
        for (int dt = 0; dt < 4; ++dt)
#pragma unroll
            for (int r = 0; r < 16; ++r) o[dt][r] *= al;

        // ---- P -> B-fragments (packed-f16 halves exchanged via shfl) ; O^T += V^T P^T ----
#pragma unroll
        for (int s = 0; s < 2; ++s) {
#pragma unroll
            for (int k = 0; k < 2; ++k) {
                unsigned aw = __builtin_bit_cast(unsigned, __builtin_amdgcn_cvt_pkrtz(sc[s][8 * k + 0], sc[s][8 * k + 1]));
                unsigned cw = __builtin_bit_cast(unsigned, __builtin_amdgcn_cvt_pkrtz(sc[s][8 * k + 2], sc[s][8 * k + 3]));
                unsigned bw = __builtin_bit_cast(unsigned, __builtin_amdgcn_cvt_pkrtz(sc[s][8 * k + 4], sc[s][8 * k + 5]));
                unsigned dw = __builtin_bit_cast(unsigned, __builtin_amdgcn_cvt_pkrtz(sc[s][8 * k + 6], sc[s][8 * k + 7]));
                unsigned pa = __shfl_xor(aw, 32, 64);
                unsigned pb = __shfl_xor(bw, 32, 64);
                unsigned pc = __shfl_xor(cw, 32, 64);
                unsigned pd = __shfl_xor(dw, 32, 64);
                u32x4 ww;
                ww[0] = hi ? pb : aw;
                ww[1] = hi ? pd : cw;
                ww[2] = hi ? bw : pa;
                ww[3] = hi ? dw : pc;
                f16x8 pf = __builtin_bit_cast(f16x8, ww);
                __builtin_amdgcn_s_setprio(1);
#pragma unroll
                for (int dt = 0; dt < 4; ++dt) {
                    f16x8 vf = *(const f16x8*)(Vb + (((dt * 32 + l31) * 128 + 64 * s + 32 * k + 16 * hi) ^ swz));
                    o[dt] = __builtin_amdgcn_mfma_f32_32x32x16_f16(vf, pf, o[dt], 0, 0, 0);
                }
                __builtin_amdgcn_s_setprio(0);
            }
        }
    }

    // ---- epilogue: transpose O^T via per-wave LDS region, coalesced stores ----
    float inv = SPLITOUT ? 1.0f : (1.0f / ls);
    if constexpr (SPLITOUT) {
        if (lane < 32) {
            size_t mi = ((size_t)sp * nb + b) * SX + qrow;
            mpart[mi] = m;
            lpart[mi] = ls;
        }
    }
    __syncthreads();   // everyone done with K/V LDS
    char* Ep = (char*)smem + wv * 4096;   // [32 q][32 d] f32, swizzled
    for (int dt = 0; dt < 4; ++dt) {
#pragma unroll
        for (int g = 0; g < 4; ++g)
#pragma unroll
            for (int t4 = 0; t4 < 4; ++t4) {
                int r = g * 4 + t4;
                int dl = t4 + 8 * g + 4 * hi;
                *(float*)(Ep + (l31 * 128 + ((dl * 4) ^ swz))) = o[dt][r] * inv;
            }
        __syncthreads();
        if constexpr (SPLITOUT) {
            _Float16* Ob = Opart + ((size_t)sp * nb + b) * SX * DD;
#pragma unroll
            for (int i = 0; i < 2; ++i) {
                int id = i * 64 + lane;
                int q2 = id >> 2, c8 = id & 3;
                int qs = (q2 & 7) << 4;
                f32x4 e0 = *(const f32x4*)(Ep + (q2 * 128 + ((c8 * 32) ^ qs)));
                f32x4 e1 = *(const f32x4*)(Ep + (q2 * 128 + ((c8 * 32 + 16) ^ qs)));
                f16x8 h;
#pragma unroll
                for (int j = 0; j < 4; ++j) { h[j] = (_Float16)e0[j]; h[4 + j] = (_Float16)e1[j]; }
                *(f16x8*)(Ob + (size_t)(qbase + wv * 32 + q2) * DD + dt * 32 + c8 * 8) = h;
            }
        } else {
            float* ob = og + (size_t)b * SX * DD;
#pragma unroll
            for (int i = 0; i < 4; ++i) {
                int id = i * 64 + lane;
                int q2 = id >> 3, ch = id & 7;
                int qs = (q2 & 7) << 4;
                f32x4 e = *(const f32x4*)(Ep + (q2 * 128 + ((ch * 16) ^ qs)));
                size_t gi = (size_t)(qbase + wv * 32 + q2) * DD + dt * 32 + ch * 4;
                f32x4 xv = *(const f32x4*)(xb + gi);
                f32x4 rs;
#pragma unroll
                for (int j = 0; j < 4; ++j) rs[j] = xv[j] + e[j];
                *(f32x4*)(ob + gi) = rs;
            }
        }
        __syncthreads();
    }
}

// ---------------- combine nsplit partials + residual ----------------
__global__ __launch_bounds__(256) void combine(const float* __restrict__ x,
    const _Float16* __restrict__ Opart, const float* __restrict__ mpart,
    const float* __restrict__ lpart, float* __restrict__ out, int nb, int nsplit)
{
    int tid = (int)threadIdx.x;
    int gr = blockIdx.x * 8 + (tid >> 5);
    int c = tid & 31;
    size_t nrows = (size_t)nb * SX;
    float M = -3.0e38f;
    for (int s = 0; s < nsplit; ++s) M = fmaxf(M, mpart[(size_t)s * nrows + gr]);
    float wsum = 0.f;
    float acc[4] = {0.f, 0.f, 0.f, 0.f};
    for (int s = 0; s < nsplit; ++s) {
        float ms = mpart[(size_t)s * nrows + gr];
        float lv = lpart[(size_t)s * nrows + gr];
        float wv = __builtin_exp2f((ms - M) * L2E);
        wsum += wv * lv;
        f16x4 h = *(const f16x4*)(Opart + (size_t)s * nrows * DD + (size_t)gr * DD + c * 4);
#pragma unroll
        for (int j = 0; j < 4; ++j) acc[j] += wv * (float)h[j];
    }
    float inv = 1.0f / wsum;
    size_t off = (size_t)gr * DD + c * 4;
    f32x4 xv = *(const f32x4*)(x + off);
    f32x4 rs;
#pragma unroll
    for (int j = 0; j < 4; ++j) rs[j] = xv[j] + acc[j] * inv;
    *(f32x4*)(out + off) = rs;
}

extern "C" void kernel_launch(void* const* d_in, const int* in_sizes, int n_in,
                              void* d_out, int out_size, void* d_ws, size_t ws_size,
                              hipStream_t stream) {
    const float* x = (const float*)d_in[0];
    const float* y = (const float*)d_in[1];
    float* out = (float*)d_out;
    int nb = in_sizes[0] / (SX * DD);

    size_t yTsz = (size_t)nb * DD * SY * sizeof(_Float16);
    auto opsz = [&](int n) { return (size_t)n * nb * SX * DD * sizeof(_Float16); };
    auto mlsz = [&](int n) { return (size_t)n * nb * SX * sizeof(float); };
    char* w = (char*)d_ws;
    _Float16* yT = (_Float16*)w;
    bool haveYT = yTsz <= ws_size;

    int nsplit = 0;
    if (haveYT) {
        if (yTsz + opsz(4) + 2 * mlsz(4) <= ws_size) nsplit = 4;
        else if (yTsz + opsz(2) + 2 * mlsz(2) <= ws_size) nsplit = 2;
    }

    if (haveYT)
        prepass<<<dim3((SY / 64) * (DD / 64), nb), 256, 0, stream>>>(y, yT);

    if (nsplit >= 2) {
        _Float16* Op = (_Float16*)(w + yTsz);
        float* mp = (float*)(w + yTsz + opsz(nsplit));
        float* lp = mp + (size_t)nsplit * nb * SX;
        attn_fwd<true, true><<<dim3(SX / QBLK, nb, nsplit), NTHREADS, 0, stream>>>(
            x, y, yT, out, Op, mp, lp, SY / nsplit, nb);
        combine<<<dim3(nb * SX / 8), 256, 0, stream>>>(x, Op, mp, lp, out, nb, nsplit);
    } else if (haveYT) {
        attn_fwd<false, true><<<dim3(SX / QBLK, nb, 1), NTHREADS, 0, stream>>>(
            x, y, yT, out, nullptr, nullptr, nullptr, SY, nb);
    } else {
        attn_fwd<false, false><<<dim3(SX / QBLK, nb, 1), NTHREADS, 0, stream>>>(
            x, y, nullptr, out, nullptr, nullptr, nullptr, SY, nb);
    }
}